// Round 7
// baseline (96.673 us; speedup 1.0000x reference)
//
#include <hip/hip_runtime.h>
#include <hip/hip_bf16.h>

#define NNODES 50000
#define KNBR   17
#define DF     128
#define NEDGE  (NNODES*KNBR)
#define BN_EPS 1e-5f
#define SLOPE  0.01f
#define NPAD   50048
#define NBG    ((NNODES+63)/64)      // 782 gemm blocks
#define NBS    ((NNODES+3)/4)        // 12500 scores blocks (4 waves each)

// ---- workspace layout (in 4B words) ----
#define NBLK_BN 256
#define OFF_PART 0                            // 256 blocks * 256 floats
#define OFF_SS   (NBLK_BN*256)                // scale[128], shift[128]
#define OFF_T    (OFF_SS + 256)               // T32: NPAD rows x 64 uints (128 fp16 of Ht)
#define OFF_Y    (OFF_T + NPAD*64)            // Y32: NPAD rows x 64 uints (128 fp16 of Out)

typedef __fp16  h2_t   __attribute__((ext_vector_type(2)));
typedef short   short8 __attribute__((ext_vector_type(8)));
typedef float   f32x4  __attribute__((ext_vector_type(4)));
typedef float   f32x2  __attribute__((ext_vector_type(2)));

__device__ __forceinline__ unsigned pack2bf(float x, float y) {
    __hip_bfloat16 a = __float2bfloat16(x), b = __float2bfloat16(y);
    unsigned short ua = __builtin_bit_cast(unsigned short, a);
    unsigned short ub = __builtin_bit_cast(unsigned short, b);
    return (unsigned)ua | ((unsigned)ub << 16);
}
__device__ __forceinline__ unsigned pack2h(float x, float y) {
    auto h = __builtin_amdgcn_cvt_pkrtz(x, y);
    return __builtin_bit_cast(unsigned, h);
}

// ---------------- K1: BatchNorm stats (partial sums, no atomics) -------------
__global__ __launch_bounds__(256) void bn_stats(const float* __restrict__ H,
                                                float* __restrict__ part) {
    const int tid = threadIdx.x;
    const int cg = tid & 31;
    const int rg = tid >> 5;
    const float4* H4 = (const float4*)H;
    float4 s = {0,0,0,0}, q = {0,0,0,0};
    for (int r = blockIdx.x*8 + rg; r < NNODES; r += gridDim.x*8) {
        float4 v = H4[r*32 + cg];
        s.x += v.x; s.y += v.y; s.z += v.z; s.w += v.w;
        q.x = fmaf(v.x, v.x, q.x); q.y = fmaf(v.y, v.y, q.y);
        q.z = fmaf(v.z, v.z, q.z); q.w = fmaf(v.w, v.w, q.w);
    }
    __shared__ float red[8][32][8];
    red[rg][cg][0] = s.x; red[rg][cg][1] = s.y; red[rg][cg][2] = s.z; red[rg][cg][3] = s.w;
    red[rg][cg][4] = q.x; red[rg][cg][5] = q.y; red[rg][cg][6] = q.z; red[rg][cg][7] = q.w;
    __syncthreads();
    float v = 0.f;
    const int cg2 = tid >> 3, slot = tid & 7;
    #pragma unroll
    for (int g = 0; g < 8; ++g) v += red[g][cg2][slot];
    part[blockIdx.x*256 + tid] = v;
}

// ---------------- K2: finalize -> scale/shift --------------------------------
__global__ __launch_bounds__(256) void bn_finalize(const float* __restrict__ part,
                                                   const float* __restrict__ gamma,
                                                   const float* __restrict__ beta,
                                                   float* __restrict__ ss) {
    __shared__ float tot[256];
    const int t = threadIdx.x;
    float v = 0.f;
    for (int b = 0; b < NBLK_BN; ++b) v += part[b*256 + t];
    tot[t] = v;
    __syncthreads();
    if (t < 128) {
        const int cg = t >> 2, sl = t & 3;
        const float sum = tot[cg*8 + sl];
        const float sq  = tot[cg*8 + 4 + sl];
        const float mean = sum * (1.0f/NNODES);
        const float var  = sq * (1.0f/NNODES) - mean*mean;
        const float sc = rsqrtf(var + BN_EPS) * gamma[t];
        ss[t]       = sc;
        ss[128 + t] = beta[t] - mean*sc;
    }
}

// ---------------- gemm body: one 64x128 tile of Hn@W+b -> fp16 table ---------
// 256 thr (4 waves); wave wc covers cols [32wc,32wc+32); K-steps of 32.
__device__ __forceinline__ void gemm_body(const float* __restrict__ H,
                                          const float* __restrict__ ss,
                                          const float* __restrict__ W,
                                          const float* __restrict__ bias,
                                          unsigned* __restrict__ dst,
                                          int bid, int tid,
                                          short (*As)[48], short (*Bs)[48]) {
    const int lane = tid & 63;
    const int wc   = tid >> 6;
    const int row0 = bid * 64;
    const float4* H4  = (const float4*)H;
    const float4* ss4 = (const float4*)ss;

    f32x4 acc[4][2];
    #pragma unroll
    for (int a = 0; a < 4; ++a)
        #pragma unroll
        for (int b = 0; b < 2; ++b) acc[a][b] = (f32x4){0,0,0,0};

    const int lrow = lane & 15, lk = lane >> 4;

    for (int s = 0; s < 4; ++s) {
        __syncthreads();
        { // stage A (BN applied, fp32 -> bf16): row r=tid>>2, k-group cq=tid&3
            const int r = tid >> 2, cq = tid & 3;
            const int row = row0 + r;
            float4 h0 = {0,0,0,0}, h1 = {0,0,0,0};
            if (row < NNODES) {
                h0 = H4[(size_t)row*32 + s*8 + cq*2];
                h1 = H4[(size_t)row*32 + s*8 + cq*2 + 1];
            }
            const float4 sc0 = ss4[s*8 + cq*2],      sc1 = ss4[s*8 + cq*2 + 1];
            const float4 sh0 = ss4[32 + s*8 + cq*2], sh1 = ss4[32 + s*8 + cq*2 + 1];
            uint4 aw;
            aw.x = pack2bf(fmaf(h0.x, sc0.x, sh0.x), fmaf(h0.y, sc0.y, sh0.y));
            aw.y = pack2bf(fmaf(h0.z, sc0.z, sh0.z), fmaf(h0.w, sc0.w, sh0.w));
            aw.z = pack2bf(fmaf(h1.x, sc1.x, sh1.x), fmaf(h1.y, sc1.y, sh1.y));
            aw.w = pack2bf(fmaf(h1.z, sc1.z, sh1.z), fmaf(h1.w, sc1.w, sh1.w));
            const int g = cq ^ ((r >> 2) & 3);
            *(uint4*)&As[r][g*8] = aw;
        }
        { // stage B: col c = tid&127, k-half kh = tid>>7 (16 ks)
            const int c  = tid & 127;
            const int kh = tid >> 7;
            float v[16];
            #pragma unroll
            for (int i = 0; i < 16; ++i)
                v[i] = W[(size_t)(s*32 + kh*16 + i)*128 + c];
            uint4 b0, b1;
            b0.x = pack2bf(v[0],v[1]);   b0.y = pack2bf(v[2],v[3]);
            b0.z = pack2bf(v[4],v[5]);   b0.w = pack2bf(v[6],v[7]);
            b1.x = pack2bf(v[8],v[9]);   b1.y = pack2bf(v[10],v[11]);
            b1.z = pack2bf(v[12],v[13]); b1.w = pack2bf(v[14],v[15]);
            const int xr = (c >> 2) & 3;
            *(uint4*)&Bs[c][((2*kh)   ^ xr)*8] = b0;
            *(uint4*)&Bs[c][((2*kh+1) ^ xr)*8] = b1;
        }
        __syncthreads();
        short8 af[4], bf[2];
        #pragma unroll
        for (int mt = 0; mt < 4; ++mt) {
            const int r = mt*16 + lrow;
            const int g = lk ^ ((r >> 2) & 3);
            af[mt] = *(const short8*)&As[r][g*8];
        }
        #pragma unroll
        for (int nt = 0; nt < 2; ++nt) {
            const int cr = wc*32 + nt*16 + lrow;
            const int g  = lk ^ ((cr >> 2) & 3);
            bf[nt] = *(const short8*)&Bs[cr][g*8];
        }
        #pragma unroll
        for (int mt = 0; mt < 4; ++mt)
            #pragma unroll
            for (int nt = 0; nt < 2; ++nt)
                acc[mt][nt] = __builtin_amdgcn_mfma_f32_16x16x32_bf16(
                    af[mt], bf[nt], acc[mt][nt], 0, 0, 0);
    }

    // epilogue: +bias, pack fp16 col-pairs via shfl_xor(1), store dwords
    float bv[2];
    #pragma unroll
    for (int nt = 0; nt < 2; ++nt)
        bv[nt] = bias[wc*32 + nt*16 + lrow];
    const int isodd = lane & 1;
    const int cp8   = (lane & 15) >> 1;
    #pragma unroll
    for (int mt = 0; mt < 4; ++mt) {
        #pragma unroll
        for (int reg = 0; reg < 4; ++reg) {
            const float a = acc[mt][0][reg] + bv[0];
            const float b = acc[mt][1][reg] + bv[1];
            const float send = isodd ? a : b;
            const float got  = __shfl_xor(send, 1);
            const float lo = isodd ? got : a;
            const float hi = isodd ? b   : got;
            const unsigned pk = pack2h(lo, hi);
            const int row = row0 + mt*16 + (lane >> 4)*4 + reg;
            const int dw  = wc*16 + isodd*8 + cp8;
            if (row < NNODES) dst[(size_t)row*64 + dw] = pk;
        }
    }
}

// ---------------- scores body: one wave per node -----------------------------
__device__ __forceinline__ float merge2(float A, float B, int lane, int m) {
    const bool hi = (lane & m) != 0;
    float t = hi ? A : B;
    t = __shfl_xor(t, m);
    return (hi ? B : A) + t;
}

__device__ __forceinline__ void scores_body(const unsigned* __restrict__ T32,
                                            const int* __restrict__ col,
                                            float* __restrict__ Aout,
                                            int bid, int tid) {
    const int lane = tid & 63;
    const int i    = (bid*256 + tid) >> 6;
    if (i >= NNODES) return;

    const h2_t a = __builtin_bit_cast(h2_t, T32[(size_t)i*64 + lane]);

    int myj = 0;
    if (lane < KNBR) myj = col[i*KNBR + lane];

    float p[KNBR];
    #pragma unroll
    for (int k = 0; k < KNBR; ++k) {
        const int j = __builtin_amdgcn_readlane(myj, k);
        const unsigned v = T32[(size_t)j*64 + lane];
        p[k] = __builtin_amdgcn_fdot2(a, __builtin_bit_cast(h2_t, v), 0.0f, false);
    }

    float q0 = merge2(p[0],  p[1],  lane, 1);
    float q1 = merge2(p[2],  p[3],  lane, 1);
    float q2 = merge2(p[4],  p[5],  lane, 1);
    float q3 = merge2(p[6],  p[7],  lane, 1);
    float q4 = merge2(p[8],  p[9],  lane, 1);
    float q5 = merge2(p[10], p[11], lane, 1);
    float q6 = merge2(p[12], p[13], lane, 1);
    float q7 = merge2(p[14], p[15], lane, 1);
    float q8 = p[16] + __shfl_xor(p[16], 1);

    float r0 = merge2(q0, q1, lane, 2);
    float r1 = merge2(q2, q3, lane, 2);
    float r2 = merge2(q4, q5, lane, 2);
    float r3 = merge2(q6, q7, lane, 2);
    float r4 = q8 + __shfl_xor(q8, 2);

    float s0 = merge2(r0, r1, lane, 4);
    float s1 = merge2(r2, r3, lane, 4);
    float s2 = r4 + __shfl_xor(r4, 4);

    float t0 = merge2(s0, s1, lane, 8);
    float t1 = s2 + __shfl_xor(s2, 8);

    float u = merge2(t0, t1, lane, 16);
    u += __shfl_xor(u, 32);

    const float sig = 1.0f / (1.0f + __expf(-u));
    const float e   = __expf(sig);
    const float me  = ((lane & 31) < KNBR) ? e : 0.0f;
    float S = me;
    S += __shfl_xor(S, 1);  S += __shfl_xor(S, 2);  S += __shfl_xor(S, 4);
    S += __shfl_xor(S, 8);  S += __shfl_xor(S, 16);
    if (lane < KNBR) Aout[(size_t)i*KNBR + lane] = e / S;
}

// ---------------- K3: T = Hn@Wt + bt ----------------------------------------
__global__ __launch_bounds__(256) void gemm_T(const float* __restrict__ H,
                                              const float* __restrict__ ss,
                                              const float* __restrict__ Wt,
                                              const float* __restrict__ bt,
                                              unsigned* __restrict__ T32) {
    __shared__ short As[64][48];
    __shared__ short Bs[128][48];
    gemm_body(H, ss, Wt, bt, T32, blockIdx.x, threadIdx.x, As, Bs);
}

// ---------------- K4: [ Y = Hn@Wo + bo ] || [ scores + softmax -> A ] --------
__global__ __launch_bounds__(256) void ygemm_scores(const float* __restrict__ H,
                                                    const float* __restrict__ ss,
                                                    const float* __restrict__ Wo,
                                                    const float* __restrict__ bo,
                                                    unsigned* __restrict__ Y32,
                                                    const unsigned* __restrict__ T32,
                                                    const int* __restrict__ col,
                                                    float* __restrict__ Aout) {
    __shared__ short As[64][48];
    __shared__ short Bs[128][48];
    if (blockIdx.x < NBG) {
        gemm_body(H, ss, Wo, bo, Y32, blockIdx.x, threadIdx.x, As, Bs);
    } else {
        scores_body(T32, col, Aout, blockIdx.x - NBG, threadIdx.x);
    }
}

// ---------------- K5: A-weighted aggregation + LeakyReLU ---------------------
__global__ __launch_bounds__(256) void attn_agg(const unsigned* __restrict__ Y32,
                                                const int* __restrict__ col,
                                                const float* __restrict__ Aout,
                                                float* __restrict__ outF) {
    const int tid  = threadIdx.x;
    const int lane = tid & 63;
    const int i    = (blockIdx.x*256 + tid) >> 6;
    if (i >= NNODES) return;

    int   myj = 0;
    float myA = 0.f;
    if (lane < KNBR) {
        myj = col[i*KNBR + lane];
        myA = Aout[(size_t)i*KNBR + lane];
    }
    const int Abits = __builtin_bit_cast(int, myA);

    float acc0 = 0.f, acc1 = 0.f;
    #pragma unroll
    for (int k = 0; k < KNBR; ++k) {
        const int j = __builtin_amdgcn_readlane(myj, k);
        const float ak = __builtin_bit_cast(float, __builtin_amdgcn_readlane(Abits, k));
        const h2_t y = __builtin_bit_cast(h2_t, Y32[(size_t)j*64 + lane]);
        acc0 = fmaf(ak, (float)y.x, acc0);
        acc1 = fmaf(ak, (float)y.y, acc1);
    }
    acc0 = (acc0 >= 0.f) ? acc0 : SLOPE*acc0;
    acc1 = (acc1 >= 0.f) ? acc1 : SLOPE*acc1;
    f32x2 o = {acc0, acc1};
    __builtin_nontemporal_store(o, (f32x2*)&outF[(size_t)i*DF + 2*lane]);
}

extern "C" void kernel_launch(void* const* d_in, const int* in_sizes, int n_in,
                              void* d_out, int out_size, void* d_ws, size_t ws_size,
                              hipStream_t stream) {
    const float* H     = (const float*)d_in[0];
    const int*   col   = (const int*)  d_in[1];
    // d_in[2] = row (== e/17 analytically, unused)
    const float* gamma = (const float*)d_in[3];
    const float* beta  = (const float*)d_in[4];
    const float* Wt    = (const float*)d_in[5];
    const float* bt    = (const float*)d_in[6];
    const float* Wo    = (const float*)d_in[7];
    const float* bo    = (const float*)d_in[8];

    float* ws   = (float*)d_ws;
    float* part = ws + OFF_PART;
    float* ss   = ws + OFF_SS;
    unsigned* T32 = (unsigned*)(ws + OFF_T);
    unsigned* Y32 = (unsigned*)(ws + OFF_Y);

    float* outF = (float*)d_out;
    float* Aout = outF + (size_t)NNODES*DF;

    bn_stats    <<<dim3(NBLK_BN), dim3(256), 0, stream>>>(H, part);
    bn_finalize <<<dim3(1),       dim3(256), 0, stream>>>(part, gamma, beta, ss);
    gemm_T      <<<dim3(NBG),     dim3(256), 0, stream>>>(H, ss, Wt, bt, T32);
    ygemm_scores<<<dim3(NBG+NBS), dim3(256), 0, stream>>>(H, ss, Wo, bo, Y32, T32, col, Aout);
    attn_agg    <<<dim3(NBS),     dim3(256), 0, stream>>>(Y32, col, Aout, outF);
}